// Round 1
// baseline (1632.823 us; speedup 1.0000x reference)
//
#include <hip/hip_runtime.h>
#include <hip/hip_bf16.h>

#define NN 10000
#define RR 16
#define NBASE 30
#define EE 160000
#define KTOT 4352   // (RR+1)*256
#define HIDF 256
#define OUTF 128

typedef __attribute__((ext_vector_type(8))) short bf16x8;
typedef __attribute__((ext_vector_type(4))) short s16x4;
typedef __attribute__((ext_vector_type(4))) float f32x4;

static __device__ __forceinline__ short f2bf(float f) {
    union { float f; unsigned u; } v; v.f = f;
    unsigned r = v.u + 0x7FFFu + ((v.u >> 16) & 1u);
    return (short)(r >> 16);
}

// Build transposed stacked weights: WT[o][k], k = r*256+i for r<16, k-4096=i for root.
__global__ void build_w_k(const float* __restrict__ basis1, const float* __restrict__ comp1,
                          const float* __restrict__ root1,
                          const float* __restrict__ basis2, const float* __restrict__ comp2,
                          const float* __restrict__ root2,
                          short* __restrict__ WT1, short* __restrict__ WT2) {
    long idx = (long)blockIdx.x * blockDim.x + threadIdx.x;
    const long n1 = (long)HIDF * KTOT;
    if (idx < n1) {
        int o = (int)(idx / KTOT), k = (int)(idx % KTOT);
        float v;
        if (k < RR * 256) {
            int r = k >> 8, i = k & 255;
            float s = 0.f;
            #pragma unroll
            for (int b = 0; b < NBASE; b++)
                s += comp1[r * NBASE + b] * basis1[((long)b * 256 + i) * 256 + o];
            v = s;
        } else {
            v = root1[(long)(k - RR * 256) * 256 + o];
        }
        WT1[(long)o * KTOT + k] = f2bf(v);
    } else {
        idx -= n1;
        if (idx < (long)OUTF * KTOT) {
            int o = (int)(idx / KTOT), k = (int)(idx % KTOT);
            float v;
            if (k < RR * 256) {
                int r = k >> 8, i = k & 255;
                float s = 0.f;
                #pragma unroll
                for (int b = 0; b < NBASE; b++)
                    s += comp2[r * NBASE + b] * basis2[((long)b * 256 + i) * 128 + o];
                v = s;
            } else {
                v = root2[(long)(k - RR * 256) * 128 + o];
            }
            WT2[(long)o * KTOT + k] = f2bf(v);
        }
    }
}

__global__ void count_k(const int* __restrict__ dst, const int* __restrict__ et,
                        float* __restrict__ cnt) {
    int e = blockIdx.x * 256 + threadIdx.x;
    if (e < EE) unsafeAtomicAdd(&cnt[dst[e] * RR + et[e]], 1.0f);
}

__global__ void inv_k(float* __restrict__ cnt) {
    int i = blockIdx.x * 256 + threadIdx.x;
    if (i < NN * RR) cnt[i] = 1.0f / fmaxf(cnt[i], 1.0f);
}

// One wave per edge: A[dst*R+et][0:256] += x[src][0:256] * invcnt[seg]
__global__ void scatter_k(const int* __restrict__ src, const int* __restrict__ dst,
                          const int* __restrict__ et, const float* __restrict__ invc,
                          const float* __restrict__ X, float* __restrict__ A) {
    int e = blockIdx.x * 4 + (threadIdx.x >> 6);
    int lane = threadIdx.x & 63;
    if (e >= EE) return;
    int s = src[e], d = dst[e], t = et[e];
    int seg = d * RR + t;
    float sc = invc[seg];
    float4 v = *(const float4*)(X + (long)s * 256 + lane * 4);
    float* a = A + (long)seg * 256 + lane * 4;
    unsafeAtomicAdd(a + 0, v.x * sc);
    unsafeAtomicAdd(a + 1, v.y * sc);
    unsafeAtomicAdd(a + 2, v.z * sc);
    unsafeAtomicAdd(a + 3, v.w * sc);
}

// C[m][o] = sum_k Abig[m][k] * WT[o][k] (+bias, opt ReLU)
// Abig row m, k=r*256+i: r<16 -> A[(m*16+r)*256+i] (already mean), r==16 -> Xroot[m][i]
// BM=32, BK=32, 4 waves, each wave 32 x (BN/4) via 2 x FN frags of 16x16.
template <int BN, bool RELU>
__global__ __launch_bounds__(256, 2) void gemm_k(const float* __restrict__ A,
                                                 const float* __restrict__ Xroot,
                                                 const short* __restrict__ WT,
                                                 const float* __restrict__ bias,
                                                 float* __restrict__ C) {
    constexpr int FN = BN / 64;
    __shared__ __align__(16) short As[32 * 40];
    __shared__ __align__(16) short Bs[BN * 40];
    const int tid = threadIdx.x;
    const int lane = tid & 63;
    const int w = tid >> 6;
    const int m0 = blockIdx.x * 32;

    f32x4 acc[2][FN] = {};

    const int arow = tid >> 3;  // 0..31
    const int agrp = tid & 7;   // 0..7, 4 floats each
    const int am = m0 + arow;
    const int n0 = w * (BN / 4);
    const int ks = (lane >> 4) << 3;
    const int al = lane & 15;

    for (int k0 = 0; k0 < KTOT; k0 += 32) {
        // stage A tile (f32 -> bf16)
        {
            float4 v = make_float4(0.f, 0.f, 0.f, 0.f);
            if (am < NN) {
                const int rel = k0 >> 8;
                const float* p;
                if (rel < RR)
                    p = A + ((long)(am * RR + rel) << 8) + (k0 & 255) + agrp * 4;
                else
                    p = Xroot + ((long)am << 8) + (k0 & 255) + agrp * 4;
                v = *(const float4*)p;
            }
            s16x4 pk = { f2bf(v.x), f2bf(v.y), f2bf(v.z), f2bf(v.w) };
            *(s16x4*)&As[arow * 40 + agrp * 4] = pk;
        }
        // stage B tile (bf16 copy, already transposed [o][k])
        #pragma unroll
        for (int c = tid; c < BN * 4; c += 256) {
            int o = c >> 2, grp = c & 3;
            *(uint4*)&Bs[o * 40 + grp * 8] =
                *(const uint4*)&WT[(long)o * KTOT + k0 + grp * 8];
        }
        __syncthreads();

        bf16x8 a0 = *(const bf16x8*)&As[al * 40 + ks];
        bf16x8 a1 = *(const bf16x8*)&As[(al + 16) * 40 + ks];
        #pragma unroll
        for (int fn = 0; fn < FN; fn++) {
            bf16x8 b = *(const bf16x8*)&Bs[(n0 + fn * 16 + al) * 40 + ks];
            acc[0][fn] = __builtin_amdgcn_mfma_f32_16x16x32_bf16(a0, b, acc[0][fn], 0, 0, 0);
            acc[1][fn] = __builtin_amdgcn_mfma_f32_16x16x32_bf16(a1, b, acc[1][fn], 0, 0, 0);
        }
        __syncthreads();
    }

    // epilogue: C/D frag layout col=lane&15, row=(lane>>4)*4+j
    #pragma unroll
    for (int fm = 0; fm < 2; fm++) {
        const int mr = m0 + fm * 16 + ((lane >> 4) << 2);
        #pragma unroll
        for (int fn = 0; fn < FN; fn++) {
            const int o = n0 + fn * 16 + al;
            const float bb = bias[o];
            #pragma unroll
            for (int j = 0; j < 4; j++) {
                int m = mr + j;
                if (m < NN) {
                    float vv = acc[fm][fn][j] + bb;
                    if (RELU) vv = fmaxf(vv, 0.f);
                    C[(long)m * BN + o] = vv;
                }
            }
        }
    }
}

extern "C" void kernel_launch(void* const* d_in, const int* in_sizes, int n_in,
                              void* d_out, int out_size, void* d_ws, size_t ws_size,
                              hipStream_t stream) {
    const float* x      = (const float*)d_in[0];
    const int*   ei     = (const int*)d_in[1];
    const int*   et     = (const int*)d_in[2];
    const float* basis1 = (const float*)d_in[3];
    const float* comp1  = (const float*)d_in[4];
    const float* root1  = (const float*)d_in[5];
    const float* bias1  = (const float*)d_in[6];
    const float* basis2 = (const float*)d_in[7];
    const float* comp2  = (const float*)d_in[8];
    const float* root2  = (const float*)d_in[9];
    const float* bias2  = (const float*)d_in[10];
    const int* src = ei;
    const int* dst = ei + EE;

    // workspace layout (f32 units unless noted):
    // A    : NN*RR*256            = 40,960,000 f32  (163.84 MB)
    // cnt  : NN*RR                = 160,000 f32     (invcnt after inv_k; reused both layers)
    // H    : NN*256               = 2,560,000 f32
    // WT1  : 256*4352 bf16, WT2 : 128*4352 bf16
    float* A   = (float*)d_ws;
    float* cnt = A + (long)NN * RR * 256;
    float* H   = cnt + (long)NN * RR;
    short* WT1 = (short*)(H + (long)NN * HIDF);
    short* WT2 = WT1 + (long)HIDF * KTOT;

    hipMemsetAsync(A, 0, ((long)NN * RR * 256 + (long)NN * RR) * sizeof(float), stream);
    build_w_k<<<((HIDF + OUTF) * KTOT) / 256, 256, 0, stream>>>(
        basis1, comp1, root1, basis2, comp2, root2, WT1, WT2);
    count_k<<<(EE + 255) / 256, 256, 0, stream>>>(dst, et, cnt);
    inv_k<<<(NN * RR + 255) / 256, 256, 0, stream>>>(cnt);
    scatter_k<<<EE / 4, 256, 0, stream>>>(src, dst, et, cnt, x, A);
    gemm_k<256, true><<<(NN + 31) / 32, 256, 0, stream>>>(A, x, WT1, bias1, H);
    hipMemsetAsync(A, 0, (long)NN * RR * 256 * sizeof(float), stream);
    scatter_k<<<EE / 4, 256, 0, stream>>>(src, dst, et, cnt, H, A);
    gemm_k<128, false><<<(NN + 31) / 32, 256, 0, stream>>>(A, H, WT2, bias2, (float*)d_out);
}

// Round 2
// 409.251 us; speedup vs baseline: 3.9898x; 3.9898x over previous
//
#include <hip/hip_runtime.h>
#include <hip/hip_bf16.h>

#define NN 10000
#define RR 16
#define NBASE 30
#define EE 160000
#define KTOT 4352   // (RR+1)*256
#define HIDF 256
#define OUTF 128
#define NSEG (NN * RR)

typedef __attribute__((ext_vector_type(8))) short bf16x8;
typedef __attribute__((ext_vector_type(4))) short s16x4;
typedef __attribute__((ext_vector_type(4))) float f32x4;

static __device__ __forceinline__ short f2bf(float f) {
    union { float f; unsigned u; } v; v.f = f;
    unsigned r = v.u + 0x7FFFu + ((v.u >> 16) & 1u);
    return (short)(r >> 16);
}

// ---- weight build: Wtmp[k][o] f32 (coalesced in o), k = r*256+i, r==16 -> root ----
template <int OUT>
__global__ void w1_k(const float* __restrict__ basis, const float* __restrict__ comp,
                     const float* __restrict__ root, float* __restrict__ Wtmp) {
    long idx = (long)blockIdx.x * 256 + threadIdx.x;
    if (idx >= (long)KTOT * OUT) return;
    int k = (int)(idx / OUT), o = (int)(idx % OUT);
    int r = k >> 8, i = k & 255;
    float v;
    if (r < RR) {
        float s = 0.f;
        #pragma unroll
        for (int b = 0; b < NBASE; b++)
            s += comp[r * NBASE + b] * basis[((long)b * 256 + i) * OUT + o];
        v = s;
    } else {
        v = root[(long)i * OUT + o];
    }
    Wtmp[idx] = v;
}

// ---- transpose + cvt: WT[o][k] bf16 from Wtmp[k][o] f32 ----
template <int OUT>
__global__ void tr_k(const float* __restrict__ Wtmp, short* __restrict__ WT) {
    __shared__ float t[32][33];
    int k0 = blockIdx.x * 32, o0 = blockIdx.y * 32;
    int tx = threadIdx.x & 31, ty = threadIdx.x >> 5;  // ty 0..7
    #pragma unroll
    for (int dy = 0; dy < 32; dy += 8)
        t[ty + dy][tx] = Wtmp[(long)(k0 + ty + dy) * OUT + o0 + tx];
    __syncthreads();
    #pragma unroll
    for (int dy = 0; dy < 32; dy += 8)
        WT[(long)(o0 + ty + dy) * KTOT + k0 + tx] = f2bf(t[tx][ty + dy]);
}

// ---- CSR build ----
__global__ void count_k(const int* __restrict__ dst, const int* __restrict__ et,
                        int* __restrict__ cnt) {
    int e = blockIdx.x * 256 + threadIdx.x;
    if (e < EE) atomicAdd(&cnt[dst[e] * RR + et[e]], 1);
}

__global__ void scan1_k(const int* __restrict__ cnt, int* __restrict__ incl,
                        int* __restrict__ bsum) {
    __shared__ int s[256];
    int i = blockIdx.x * 256 + threadIdx.x;
    int v = (i < NSEG) ? cnt[i] : 0;
    s[threadIdx.x] = v;
    __syncthreads();
    for (int off = 1; off < 256; off <<= 1) {
        int u = (threadIdx.x >= off) ? s[threadIdx.x - off] : 0;
        __syncthreads();
        s[threadIdx.x] += u;
        __syncthreads();
    }
    if (i < NSEG) incl[i] = s[threadIdx.x];
    if (threadIdx.x == 255) bsum[blockIdx.x] = s[255];
}

__global__ void scan2_k(int* __restrict__ bsum, int nb) {
    __shared__ int s[1024];
    int t = threadIdx.x;
    s[t] = (t < nb) ? bsum[t] : 0;
    __syncthreads();
    for (int off = 1; off < 1024; off <<= 1) {
        int u = (t >= off) ? s[t - off] : 0;
        __syncthreads();
        s[t] += u;
        __syncthreads();
    }
    if (t < nb) bsum[t] = s[t];
}

__global__ void scan3_k(const int* __restrict__ cnt, const int* __restrict__ incl,
                        const int* __restrict__ bsum, int* __restrict__ row_ptr,
                        int* __restrict__ fillpos) {
    int i = blockIdx.x * 256 + threadIdx.x;
    if (i >= NSEG) return;
    int off = (blockIdx.x > 0) ? bsum[blockIdx.x - 1] : 0;
    int ex = off + incl[i] - cnt[i];
    row_ptr[i] = ex;
    fillpos[i] = ex;
    if (i == 0) row_ptr[NSEG] = EE;
}

__global__ void fill_k(const int* __restrict__ src, const int* __restrict__ dst,
                       const int* __restrict__ et, int* __restrict__ fillpos,
                       int* __restrict__ esrc) {
    int e = blockIdx.x * 256 + threadIdx.x;
    if (e < EE) {
        int seg = dst[e] * RR + et[e];
        int p = atomicAdd(&fillpos[seg], 1);
        esrc[p] = src[e];
    }
}

// ---- gather-mean into Abig[(m*17+rel)*256 + c] bf16, one wave per segment ----
__global__ void agg_k(const int* __restrict__ rp, const int* __restrict__ esrc,
                      const float* __restrict__ X, short* __restrict__ Abig) {
    int wid = (blockIdx.x * 256 + threadIdx.x) >> 6;
    int lane = threadIdx.x & 63;
    int nw = (gridDim.x * 256) >> 6;
    for (int seg = wid; seg < NSEG; seg += nw) {
        int m = seg >> 4, rel = seg & 15;
        int b = rp[seg], e = rp[seg + 1];
        float4 acc = make_float4(0.f, 0.f, 0.f, 0.f);
        for (int j = b; j < e; j++) {
            const float* p = X + (long)esrc[j] * 256 + lane * 4;
            float4 v = *(const float4*)p;
            acc.x += v.x; acc.y += v.y; acc.z += v.z; acc.w += v.w;
        }
        float inv = (e > b) ? 1.f / (float)(e - b) : 0.f;
        s16x4 pk = { f2bf(acc.x * inv), f2bf(acc.y * inv),
                     f2bf(acc.z * inv), f2bf(acc.w * inv) };
        *(s16x4*)&Abig[((long)m * 17 + rel) * 256 + lane * 4] = pk;
    }
}

// ---- root-feature slot: Abig[(m*17+16)*256 + c] = bf16(Xf32[m][c]) ----
__global__ void cvt_root_k(const float* __restrict__ X, short* __restrict__ Abig) {
    int i = blockIdx.x * 256 + threadIdx.x;  // one thread per 4 cols
    if (i >= NN * 64) return;
    int m = i >> 6, g = i & 63;
    float4 v = *(const float4*)(X + (long)m * 256 + g * 4);
    s16x4 pk = { f2bf(v.x), f2bf(v.y), f2bf(v.z), f2bf(v.w) };
    *(s16x4*)&Abig[((long)m * 17 + 16) * 256 + g * 4] = pk;
}

// ---- GEMM: C[m][o] = sum_k Abig[m][k]*WT[o][k] (+bias, opt ReLU) ----
template <int BN, bool RELU>
__global__ __launch_bounds__(256, 2) void gemm_k(const short* __restrict__ Abig,
                                                 const short* __restrict__ WT,
                                                 const float* __restrict__ bias,
                                                 float* __restrict__ C) {
    constexpr int FN = BN / 64;
    __shared__ __align__(16) short As[32 * 40];
    __shared__ __align__(16) short Bs[BN * 40];
    const int tid = threadIdx.x;
    const int lane = tid & 63;
    const int w = tid >> 6;
    const int m0 = blockIdx.x * 32;

    f32x4 acc[2][FN] = {};

    const int arow = tid >> 3;  // 0..31
    const int agrp = tid & 7;   // 0..7 (4 bf16 each)
    const int am = m0 + arow;
    const int n0 = w * (BN / 4);
    const int ks = (lane >> 4) << 3;
    const int al = lane & 15;

    for (int k0 = 0; k0 < KTOT; k0 += 32) {
        // stage A tile: 32 rows x 32 cols bf16 (contiguous per row)
        {
            s16x4 av = {};
            if (am < NN)
                av = *(const s16x4*)&Abig[(long)am * KTOT + k0 + agrp * 4];
            *(s16x4*)&As[arow * 40 + agrp * 4] = av;
        }
        // stage B tile
        #pragma unroll
        for (int c = tid; c < BN * 4; c += 256) {
            int o = c >> 2, grp = c & 3;
            *(uint4*)&Bs[o * 40 + grp * 8] =
                *(const uint4*)&WT[(long)o * KTOT + k0 + grp * 8];
        }
        __syncthreads();

        bf16x8 a0 = *(const bf16x8*)&As[al * 40 + ks];
        bf16x8 a1 = *(const bf16x8*)&As[(al + 16) * 40 + ks];
        #pragma unroll
        for (int fn = 0; fn < FN; fn++) {
            bf16x8 b = *(const bf16x8*)&Bs[(n0 + fn * 16 + al) * 40 + ks];
            acc[0][fn] = __builtin_amdgcn_mfma_f32_16x16x32_bf16(a0, b, acc[0][fn], 0, 0, 0);
            acc[1][fn] = __builtin_amdgcn_mfma_f32_16x16x32_bf16(a1, b, acc[1][fn], 0, 0, 0);
        }
        __syncthreads();
    }

    #pragma unroll
    for (int fm = 0; fm < 2; fm++) {
        const int mr = m0 + fm * 16 + ((lane >> 4) << 2);
        #pragma unroll
        for (int fn = 0; fn < FN; fn++) {
            const int o = n0 + fn * 16 + al;
            const float bb = bias[o];
            #pragma unroll
            for (int j = 0; j < 4; j++) {
                int m = mr + j;
                if (m < NN) {
                    float vv = acc[fm][fn][j] + bb;
                    if (RELU) vv = fmaxf(vv, 0.f);
                    C[(long)m * BN + o] = vv;
                }
            }
        }
    }
}

extern "C" void kernel_launch(void* const* d_in, const int* in_sizes, int n_in,
                              void* d_out, int out_size, void* d_ws, size_t ws_size,
                              hipStream_t stream) {
    const float* x      = (const float*)d_in[0];
    const int*   ei     = (const int*)d_in[1];
    const int*   et     = (const int*)d_in[2];
    const float* basis1 = (const float*)d_in[3];
    const float* comp1  = (const float*)d_in[4];
    const float* root1  = (const float*)d_in[5];
    const float* bias1  = (const float*)d_in[6];
    const float* basis2 = (const float*)d_in[7];
    const float* comp2  = (const float*)d_in[8];
    const float* root2  = (const float*)d_in[9];
    const float* bias2  = (const float*)d_in[10];
    const int* src = ei;
    const int* dst = ei + EE;

    // workspace layout
    char* p = (char*)d_ws;
    auto take = [&](size_t bytes) { char* q = p; p += (bytes + 255) & ~(size_t)255; return q; };
    short* Abig  = (short*)take((size_t)NN * 17 * 256 * 2);   // 87.0 MB
    short* WT1   = (short*)take((size_t)HIDF * KTOT * 2);     // 2.23 MB
    short* WT2   = (short*)take((size_t)OUTF * KTOT * 2);     // 1.11 MB
    float* Wtmp1 = (float*)take((size_t)KTOT * HIDF * 4);     // 4.46 MB
    float* Wtmp2 = (float*)take((size_t)KTOT * OUTF * 4);     // 2.23 MB
    float* H     = (float*)take((size_t)NN * HIDF * 4);       // 10.2 MB
    int*   cnt   = (int*)take((size_t)NSEG * 4);
    int*   incl  = (int*)take((size_t)NSEG * 4);
    int*   rowp  = (int*)take((size_t)(NSEG + 1) * 4);
    int*   fpos  = (int*)take((size_t)NSEG * 4);
    int*   bsum  = (int*)take(1024 * 4);
    int*   esrc  = (int*)take((size_t)EE * 4);

    const int NB1 = (NSEG + 255) / 256;  // 625

    hipMemsetAsync(cnt, 0, (size_t)NSEG * 4, stream);

    // weights
    w1_k<HIDF><<<(int)(((long)KTOT * HIDF + 255) / 256), 256, 0, stream>>>(basis1, comp1, root1, Wtmp1);
    w1_k<OUTF><<<(int)(((long)KTOT * OUTF + 255) / 256), 256, 0, stream>>>(basis2, comp2, root2, Wtmp2);
    {
        dim3 g1(KTOT / 32, HIDF / 32), g2(KTOT / 32, OUTF / 32);
        tr_k<HIDF><<<g1, 256, 0, stream>>>(Wtmp1, WT1);
        tr_k<OUTF><<<g2, 256, 0, stream>>>(Wtmp2, WT2);
    }

    // CSR
    count_k<<<(EE + 255) / 256, 256, 0, stream>>>(dst, et, cnt);
    scan1_k<<<NB1, 256, 0, stream>>>(cnt, incl, bsum);
    scan2_k<<<1, 1024, 0, stream>>>(bsum, NB1);
    scan3_k<<<NB1, 256, 0, stream>>>(cnt, incl, bsum, rowp, fpos);
    fill_k<<<(EE + 255) / 256, 256, 0, stream>>>(src, dst, et, fpos, esrc);

    // layer 1
    agg_k<<<2500, 256, 0, stream>>>(rowp, esrc, x, Abig);
    cvt_root_k<<<(NN * 64 + 255) / 256, 256, 0, stream>>>(x, Abig);
    gemm_k<HIDF, true><<<(NN + 31) / 32, 256, 0, stream>>>(Abig, WT1, bias1, H);

    // layer 2
    agg_k<<<2500, 256, 0, stream>>>(rowp, esrc, H, Abig);
    cvt_root_k<<<(NN * 64 + 255) / 256, 256, 0, stream>>>(H, Abig);
    gemm_k<OUTF, false><<<(NN + 31) / 32, 256, 0, stream>>>(Abig, WT2, bias2, (float*)d_out);
}

// Round 4
// 218.475 us; speedup vs baseline: 7.4737x; 1.8732x over previous
//
#include <hip/hip_runtime.h>
#include <hip/hip_bf16.h>

#define NN 10000
#define MP 10112        // 79*128, padded M for guard-free global_load_lds
#define RR 16
#define NBASE 30
#define EE 160000
#define KTOT 4352       // (RR+1)*256
#define HIDF 256
#define OUTF 128
#define NSEG (NN * RR)

typedef __attribute__((ext_vector_type(8))) short bf16x8;
typedef __attribute__((ext_vector_type(4))) short s16x4;
typedef __attribute__((ext_vector_type(4))) float f32x4;

static __device__ __forceinline__ short f2bf(float f) {
    union { float f; unsigned u; } v; v.f = f;
    unsigned r = v.u + 0x7FFFu + ((v.u >> 16) & 1u);
    return (short)(r >> 16);
}
static __device__ __forceinline__ float bf2f(short s) {
    union { unsigned u; float f; } v;
    v.u = ((unsigned)(unsigned short)s) << 16;
    return v.f;
}
static __device__ __forceinline__ void gl16(const short* g, short* l) {
    __builtin_amdgcn_global_load_lds((const __attribute__((address_space(1))) void*)g,
                                     (__attribute__((address_space(3))) void*)l, 16, 0, 0);
}

// ---- weight build: Wtmp[k][o] f32 (coalesced in o), k = r*256+i, r==16 -> root ----
template <int OUT>
__global__ void w1_k(const float* __restrict__ basis, const float* __restrict__ comp,
                     const float* __restrict__ root, float* __restrict__ Wtmp) {
    long idx = (long)blockIdx.x * 256 + threadIdx.x;
    if (idx >= (long)KTOT * OUT) return;
    int k = (int)(idx / OUT), o = (int)(idx % OUT);
    int r = k >> 8, i = k & 255;
    float v;
    if (r < RR) {
        float s = 0.f;
        #pragma unroll
        for (int b = 0; b < NBASE; b++)
            s += comp[r * NBASE + b] * basis[((long)b * 256 + i) * OUT + o];
        v = s;
    } else {
        v = root[(long)i * OUT + o];
    }
    Wtmp[idx] = v;
}

// ---- transpose + cvt: WT[o][k] bf16 from Wtmp[k][o] f32 ----
template <int OUT>
__global__ void tr_k(const float* __restrict__ Wtmp, short* __restrict__ WT) {
    __shared__ float t[32][33];
    int k0 = blockIdx.x * 32, o0 = blockIdx.y * 32;
    int tx = threadIdx.x & 31, ty = threadIdx.x >> 5;  // ty 0..7
    #pragma unroll
    for (int dy = 0; dy < 32; dy += 8)
        t[ty + dy][tx] = Wtmp[(long)(k0 + ty + dy) * OUT + o0 + tx];
    __syncthreads();
    #pragma unroll
    for (int dy = 0; dy < 32; dy += 8)
        WT[(long)(o0 + ty + dy) * KTOT + k0 + tx] = f2bf(t[tx][ty + dy]);
}

// ---- CSR build ----
__global__ void count_k(const int* __restrict__ dst, const int* __restrict__ et,
                        int* __restrict__ cnt) {
    int e = blockIdx.x * 256 + threadIdx.x;
    if (e < EE) atomicAdd(&cnt[dst[e] * RR + et[e]], 1);
}

__global__ void scan1_k(const int* __restrict__ cnt, int* __restrict__ incl,
                        int* __restrict__ bsum) {
    __shared__ int s[256];
    int i = blockIdx.x * 256 + threadIdx.x;
    int v = (i < NSEG) ? cnt[i] : 0;
    s[threadIdx.x] = v;
    __syncthreads();
    for (int off = 1; off < 256; off <<= 1) {
        int u = (threadIdx.x >= off) ? s[threadIdx.x - off] : 0;
        __syncthreads();
        s[threadIdx.x] += u;
        __syncthreads();
    }
    if (i < NSEG) incl[i] = s[threadIdx.x];
    if (threadIdx.x == 255) bsum[blockIdx.x] = s[255];
}

__global__ void scan2_k(int* __restrict__ bsum, int nb) {
    __shared__ int s[1024];
    int t = threadIdx.x;
    s[t] = (t < nb) ? bsum[t] : 0;
    __syncthreads();
    for (int off = 1; off < 1024; off <<= 1) {
        int u = (t >= off) ? s[t - off] : 0;
        __syncthreads();
        s[t] += u;
        __syncthreads();
    }
    if (t < nb) bsum[t] = s[t];
}

__global__ void scan3_k(const int* __restrict__ cnt, const int* __restrict__ incl,
                        const int* __restrict__ bsum, int* __restrict__ row_ptr,
                        int* __restrict__ fillpos) {
    int i = blockIdx.x * 256 + threadIdx.x;
    if (i >= NSEG) return;
    int off = (blockIdx.x > 0) ? bsum[blockIdx.x - 1] : 0;
    int ex = off + incl[i] - cnt[i];
    row_ptr[i] = ex;
    fillpos[i] = ex;
    if (i == 0) row_ptr[NSEG] = EE;
}

__global__ void fill_k(const int* __restrict__ src, const int* __restrict__ dst,
                       const int* __restrict__ et, int* __restrict__ fillpos,
                       int* __restrict__ esrc) {
    int e = blockIdx.x * 256 + threadIdx.x;
    if (e < EE) {
        int seg = dst[e] * RR + et[e];
        int p = atomicAdd(&fillpos[seg], 1);
        esrc[p] = src[e];
    }
}

// ---- f32 -> bf16 row convert (X only) ----
__global__ void cvtbf_k(const float* __restrict__ X, short* __restrict__ Y) {
    int i = blockIdx.x * 256 + threadIdx.x;  // one per 4 cols
    if (i >= NN * 64) return;
    float4 v = *(const float4*)(X + (long)i * 4);
    s16x4 pk = { f2bf(v.x), f2bf(v.y), f2bf(v.z), f2bf(v.w) };
    *(s16x4*)&Y[(long)i * 4] = pk;
}

// ---- gather-mean, one wave per segment, bf16 in/out ----
__global__ void agg_k(const int* __restrict__ rp, const int* __restrict__ esrc,
                      const short* __restrict__ Xbf, short* __restrict__ Abig) {
    int wid = (blockIdx.x * 256 + threadIdx.x) >> 6;
    int lane = threadIdx.x & 63;
    if (wid >= NSEG) return;
    int b = rp[wid], e = rp[wid + 1];
    float a0 = 0.f, a1 = 0.f, a2 = 0.f, a3 = 0.f;
    for (int j = b; j < e; j++) {
        s16x4 v = *(const s16x4*)&Xbf[(long)esrc[j] * 256 + lane * 4];
        a0 += bf2f(v.x); a1 += bf2f(v.y); a2 += bf2f(v.z); a3 += bf2f(v.w);
    }
    float inv = (e > b) ? 1.f / (float)(e - b) : 0.f;
    s16x4 pk = { f2bf(a0 * inv), f2bf(a1 * inv), f2bf(a2 * inv), f2bf(a3 * inv) };
    *(s16x4*)&Abig[((long)(wid >> 4) * 17 + (wid & 15)) * 256 + lane * 4] = pk;
}

// ---- root slot copy: Abig[(m*17+16)*256+..] = Xbf[m][..] ----
// FIXED (r3 bug): one thread per 8 shorts (16B). NN*32 threads, g in 0..31.
__global__ void cvt_root_k(const short* __restrict__ Xbf, short* __restrict__ Abig) {
    int i = blockIdx.x * 256 + threadIdx.x;
    if (i >= NN * 32) return;
    int m = i >> 5, g = i & 31;
    *(uint4*)&Abig[((long)m * 17 + 16) * 256 + g * 8] =
        *(const uint4*)&Xbf[(long)m * 256 + g * 8];
}

// ---- GEMM partial: Cpart[z][m][o] = sum_{k in chunk z} Abig[m][k]*WT[o][k] ----
// m97 structure: 128x128 tile, BK=32, 4 waves (2x2), 4x4 frags/wave,
// global_load_lds width-16, both-sides chunk-XOR swizzle (c ^= (row>>1)&3).
template <int NOUT, int KCH>
__global__ __launch_bounds__(256, 2) void gemm_k(const short* __restrict__ A,
                                                 const short* __restrict__ WT,
                                                 float* __restrict__ Cpart) {
    __shared__ __align__(16) short As[128 * 32];
    __shared__ __align__(16) short Bs[128 * 32];
    const int tid = threadIdx.x;
    const int lane = tid & 63;
    const int w = tid >> 6;
    const int wr = w >> 1, wc = w & 1;
    const int m0 = blockIdx.x * 128;
    const int n0 = blockIdx.y * 128;
    const int kbase = blockIdx.z * KCH;

    const int al = lane & 15;
    const int cl = lane >> 4;           // k-chunk 0..3 (8 shorts each)
    const int s = (al >> 1) & 3;        // read-side swizzle

    int aidx[4], bidx[4];
    #pragma unroll
    for (int f = 0; f < 4; f++) {
        aidx[f] = (wr * 64 + f * 16 + al) * 32 + ((cl ^ s) << 3);
        bidx[f] = (wc * 64 + f * 16 + al) * 32 + ((cl ^ s) << 3);
    }

    // staging source (write-side swizzle on the GLOBAL col, LDS dest linear)
    const int lrow = lane >> 2;                                  // 0..15
    const int scol = (((lane & 3) ^ ((lane >> 3) & 3)) << 3);    // swizzled 16B chunk
    const short* ap0 = A + (long)(m0 + w * 16 + lrow) * KTOT + kbase + scol;
    const short* ap1 = ap0 + (long)64 * KTOT;
    const short* bp0 = WT + (long)(n0 + w * 16 + lrow) * KTOT + kbase + scol;
    const short* bp1 = bp0 + (long)64 * KTOT;
    short* lA0 = &As[w * 512];
    short* lA1 = &As[2048 + w * 512];
    short* lB0 = &Bs[w * 512];
    short* lB1 = &Bs[2048 + w * 512];

    f32x4 acc[4][4] = {};

    for (int kk = 0; kk < KCH; kk += 32) {
        gl16(ap0 + kk, lA0);
        gl16(ap1 + kk, lA1);
        gl16(bp0 + kk, lB0);
        gl16(bp1 + kk, lB1);
        __syncthreads();
        bf16x8 a[4], b[4];
        #pragma unroll
        for (int f = 0; f < 4; f++) a[f] = *(const bf16x8*)&As[aidx[f]];
        #pragma unroll
        for (int f = 0; f < 4; f++) b[f] = *(const bf16x8*)&Bs[bidx[f]];
        #pragma unroll
        for (int i = 0; i < 4; i++)
            #pragma unroll
            for (int j = 0; j < 4; j++)
                acc[i][j] = __builtin_amdgcn_mfma_f32_16x16x32_bf16(a[i], b[j], acc[i][j], 0, 0, 0);
        __syncthreads();
    }

    // epilogue: C/D frag col=lane&15, row=(lane>>4)*4+j
    const int r4 = (lane >> 4) << 2;
    #pragma unroll
    for (int i = 0; i < 4; i++) {
        const int mbase = m0 + wr * 64 + i * 16 + r4;
        #pragma unroll
        for (int j = 0; j < 4; j++) {
            const int m = mbase + j;
            if (m < NN) {
                float* cp = Cpart + ((long)blockIdx.z * NN + m) * NOUT + n0 + wc * 64 + al;
                #pragma unroll
                for (int q = 0; q < 4; q++)
                    cp[q * 16] = acc[i][q][j];
            }
        }
    }
}

// ---- reduce K-partials + bias (+ReLU), output bf16 or f32 ----
template <int NOUT, int KS, bool RELU, bool BF16OUT>
__global__ void reduce_k(const float* __restrict__ Cpart, const float* __restrict__ bias,
                         void* __restrict__ out) {
    constexpr int G = NOUT / 4;
    int i = blockIdx.x * 256 + threadIdx.x;  // one per 4 cols
    if (i >= NN * G) return;
    int m = i / G, g = i % G;
    f32x4 sv = {};
    #pragma unroll
    for (int z = 0; z < KS; z++)
        sv += *(const f32x4*)&Cpart[((long)z * NN + m) * NOUT + g * 4];
    sv += *(const f32x4*)&bias[g * 4];
    if (RELU) {
        sv.x = fmaxf(sv.x, 0.f); sv.y = fmaxf(sv.y, 0.f);
        sv.z = fmaxf(sv.z, 0.f); sv.w = fmaxf(sv.w, 0.f);
    }
    if (BF16OUT) {
        s16x4 pk = { f2bf(sv.x), f2bf(sv.y), f2bf(sv.z), f2bf(sv.w) };
        *(s16x4*)((short*)out + (long)i * 4) = pk;
    } else {
        *(f32x4*)((float*)out + (long)i * 4) = sv;
    }
}

extern "C" void kernel_launch(void* const* d_in, const int* in_sizes, int n_in,
                              void* d_out, int out_size, void* d_ws, size_t ws_size,
                              hipStream_t stream) {
    const float* x      = (const float*)d_in[0];
    const int*   ei     = (const int*)d_in[1];
    const int*   et     = (const int*)d_in[2];
    const float* basis1 = (const float*)d_in[3];
    const float* comp1  = (const float*)d_in[4];
    const float* root1  = (const float*)d_in[5];
    const float* bias1  = (const float*)d_in[6];
    const float* basis2 = (const float*)d_in[7];
    const float* comp2  = (const float*)d_in[8];
    const float* root2  = (const float*)d_in[9];
    const float* bias2  = (const float*)d_in[10];
    const int* src = ei;
    const int* dst = ei + EE;

    char* p = (char*)d_ws;
    auto take = [&](size_t bytes) { char* q = p; p += (bytes + 255) & ~(size_t)255; return q; };
    short* Abig  = (short*)take((size_t)MP * 17 * 256 * 2);    // 88.0 MB (padded M)
    short* WT1   = (short*)take((size_t)HIDF * KTOT * 2);
    short* WT2   = (short*)take((size_t)OUTF * KTOT * 2);
    float* Wtmp1 = (float*)take((size_t)KTOT * HIDF * 4);
    float* Wtmp2 = (float*)take((size_t)KTOT * OUTF * 4);
    short* Xbf   = (short*)take((size_t)NN * 256 * 2);
    short* Hbf   = (short*)take((size_t)NN * 256 * 2);
    float* Cpart = (float*)take((size_t)4 * NN * 256 * 4);     // 41 MB, reused both layers
    int*   cnt   = (int*)take((size_t)NSEG * 4);
    int*   incl  = (int*)take((size_t)NSEG * 4);
    int*   rowp  = (int*)take((size_t)(NSEG + 1) * 4);
    int*   fpos  = (int*)take((size_t)NSEG * 4);
    int*   bsum  = (int*)take(1024 * 4);
    int*   esrc  = (int*)take((size_t)EE * 4);

    const int NB1 = (NSEG + 255) / 256;  // 625

    hipMemsetAsync(cnt, 0, (size_t)NSEG * 4, stream);

    // weights
    w1_k<HIDF><<<(int)(((long)KTOT * HIDF + 255) / 256), 256, 0, stream>>>(basis1, comp1, root1, Wtmp1);
    w1_k<OUTF><<<(int)(((long)KTOT * OUTF + 255) / 256), 256, 0, stream>>>(basis2, comp2, root2, Wtmp2);
    {
        dim3 g1(KTOT / 32, HIDF / 32), g2(KTOT / 32, OUTF / 32);
        tr_k<HIDF><<<g1, 256, 0, stream>>>(Wtmp1, WT1);
        tr_k<OUTF><<<g2, 256, 0, stream>>>(Wtmp2, WT2);
    }

    // CSR
    count_k<<<(EE + 255) / 256, 256, 0, stream>>>(dst, et, cnt);
    scan1_k<<<NB1, 256, 0, stream>>>(cnt, incl, bsum);
    scan2_k<<<1, 1024, 0, stream>>>(bsum, NB1);
    scan3_k<<<NB1, 256, 0, stream>>>(cnt, incl, bsum, rowp, fpos);
    fill_k<<<(EE + 255) / 256, 256, 0, stream>>>(src, dst, et, fpos, esrc);

    // X -> bf16
    cvtbf_k<<<(NN * 64 + 255) / 256, 256, 0, stream>>>(x, Xbf);

    // layer 1
    agg_k<<<(NSEG * 64 + 255) / 256, 256, 0, stream>>>(rowp, esrc, Xbf, Abig);
    cvt_root_k<<<(NN * 32 + 255) / 256, 256, 0, stream>>>(Xbf, Abig);
    {
        dim3 g(MP / 128, HIDF / 128, 4);  // KS=4, KCH=1088
        gemm_k<HIDF, 1088><<<g, 256, 0, stream>>>(Abig, WT1, Cpart);
    }
    reduce_k<HIDF, 4, true, true><<<(NN * 64 + 255) / 256, 256, 0, stream>>>(Cpart, bias1, Hbf);

    // layer 2
    agg_k<<<(NSEG * 64 + 255) / 256, 256, 0, stream>>>(rowp, esrc, Hbf, Abig);
    cvt_root_k<<<(NN * 32 + 255) / 256, 256, 0, stream>>>(Hbf, Abig);
    {
        dim3 g(MP / 128, OUTF / 128, 8);  // KS=8, KCH=544
        gemm_k<OUTF, 544><<<g, 256, 0, stream>>>(Abig, WT2, Cpart);
    }
    reduce_k<OUTF, 8, false, false><<<(NN * 32 + 255) / 256, 256, 0, stream>>>(Cpart, bias2, (float*)d_out);
}

// Round 5
// 187.088 us; speedup vs baseline: 8.7276x; 1.1678x over previous
//
#include <hip/hip_runtime.h>
#include <hip/hip_bf16.h>

#define NN 10000
#define MP 10048        // 157*64, padded M for guard-free global_load_lds
#define RR 16
#define NBASE 30
#define EE 160000
#define KTOT 4352       // (RR+1)*256
#define HIDF 256
#define OUTF 128
#define NSEG (NN * RR)

typedef __attribute__((ext_vector_type(8))) short bf16x8;
typedef __attribute__((ext_vector_type(4))) short s16x4;
typedef __attribute__((ext_vector_type(4))) float f32x4;

static __device__ __forceinline__ short f2bf(float f) {
    union { float f; unsigned u; } v; v.f = f;
    unsigned r = v.u + 0x7FFFu + ((v.u >> 16) & 1u);
    return (short)(r >> 16);
}
static __device__ __forceinline__ float bf2f(short s) {
    union { unsigned u; float f; } v;
    v.u = ((unsigned)(unsigned short)s) << 16;
    return v.f;
}
static __device__ __forceinline__ void gl16(const short* g, short* l) {
    __builtin_amdgcn_global_load_lds((const __attribute__((address_space(1))) void*)g,
                                     (__attribute__((address_space(3))) void*)l, 16, 0, 0);
}

// ---- weight build: Wtmp[k][o] f32 (coalesced in o), k = r*256+i, r==16 -> root ----
template <int OUT>
__global__ void w1_k(const float* __restrict__ basis, const float* __restrict__ comp,
                     const float* __restrict__ root, float* __restrict__ Wtmp) {
    long idx = (long)blockIdx.x * 256 + threadIdx.x;
    if (idx >= (long)KTOT * OUT) return;
    int k = (int)(idx / OUT), o = (int)(idx % OUT);
    int r = k >> 8, i = k & 255;
    float v;
    if (r < RR) {
        float s = 0.f;
        #pragma unroll
        for (int b = 0; b < NBASE; b++)
            s += comp[r * NBASE + b] * basis[((long)b * 256 + i) * OUT + o];
        v = s;
    } else {
        v = root[(long)i * OUT + o];
    }
    Wtmp[idx] = v;
}

// ---- transpose + cvt: WT[o][k] bf16 from Wtmp[k][o] f32 ----
template <int OUT>
__global__ void tr_k(const float* __restrict__ Wtmp, short* __restrict__ WT) {
    __shared__ float t[32][33];
    int k0 = blockIdx.x * 32, o0 = blockIdx.y * 32;
    int tx = threadIdx.x & 31, ty = threadIdx.x >> 5;  // ty 0..7
    #pragma unroll
    for (int dy = 0; dy < 32; dy += 8)
        t[ty + dy][tx] = Wtmp[(long)(k0 + ty + dy) * OUT + o0 + tx];
    __syncthreads();
    #pragma unroll
    for (int dy = 0; dy < 32; dy += 8)
        WT[(long)(o0 + ty + dy) * KTOT + k0 + tx] = f2bf(t[tx][ty + dy]);
}

// ---- CSR build ----
__global__ void count_k(const int* __restrict__ dst, const int* __restrict__ et,
                        int* __restrict__ cnt) {
    int e = blockIdx.x * 256 + threadIdx.x;
    if (e < EE) atomicAdd(&cnt[dst[e] * RR + et[e]], 1);
}

__global__ void scan1_k(const int* __restrict__ cnt, int* __restrict__ incl,
                        int* __restrict__ bsum) {
    __shared__ int s[256];
    int i = blockIdx.x * 256 + threadIdx.x;
    int v = (i < NSEG) ? cnt[i] : 0;
    s[threadIdx.x] = v;
    __syncthreads();
    for (int off = 1; off < 256; off <<= 1) {
        int u = (threadIdx.x >= off) ? s[threadIdx.x - off] : 0;
        __syncthreads();
        s[threadIdx.x] += u;
        __syncthreads();
    }
    if (i < NSEG) incl[i] = s[threadIdx.x];
    if (threadIdx.x == 255) bsum[blockIdx.x] = s[255];
}

__global__ void scan2_k(int* __restrict__ bsum, int nb) {
    __shared__ int s[1024];
    int t = threadIdx.x;
    s[t] = (t < nb) ? bsum[t] : 0;
    __syncthreads();
    for (int off = 1; off < 1024; off <<= 1) {
        int u = (t >= off) ? s[t - off] : 0;
        __syncthreads();
        s[t] += u;
        __syncthreads();
    }
    if (t < nb) bsum[t] = s[t];
}

__global__ void scan3_k(const int* __restrict__ cnt, const int* __restrict__ incl,
                        const int* __restrict__ bsum, int* __restrict__ row_ptr,
                        int* __restrict__ fillpos) {
    int i = blockIdx.x * 256 + threadIdx.x;
    if (i >= NSEG) return;
    int off = (blockIdx.x > 0) ? bsum[blockIdx.x - 1] : 0;
    int ex = off + incl[i] - cnt[i];
    row_ptr[i] = ex;
    fillpos[i] = ex;
    if (i == 0) row_ptr[NSEG] = EE;
}

__global__ void fill_k(const int* __restrict__ src, const int* __restrict__ dst,
                       const int* __restrict__ et, int* __restrict__ fillpos,
                       int* __restrict__ esrc) {
    int e = blockIdx.x * 256 + threadIdx.x;
    if (e < EE) {
        int seg = dst[e] * RR + et[e];
        int p = atomicAdd(&fillpos[seg], 1);
        esrc[p] = src[e];
    }
}

// ---- f32 -> bf16 row convert (X only) ----
__global__ void cvtbf_k(const float* __restrict__ X, short* __restrict__ Y) {
    int i = blockIdx.x * 256 + threadIdx.x;  // one per 4 cols
    if (i >= NN * 64) return;
    float4 v = *(const float4*)(X + (long)i * 4);
    s16x4 pk = { f2bf(v.x), f2bf(v.y), f2bf(v.z), f2bf(v.w) };
    *(s16x4*)&Y[(long)i * 4] = pk;
}

// ---- gather-mean, 2 segments per wave, 16B/lane, bf16 in/out ----
__global__ void agg_k(const int* __restrict__ rp, const int* __restrict__ esrc,
                      const short* __restrict__ Xbf, short* __restrict__ Abig) {
    int wv = (blockIdx.x * 256 + threadIdx.x) >> 6;
    int lane = threadIdx.x & 63;
    int seg = wv * 2 + (lane >> 5);
    if (seg >= NSEG) return;
    int l5 = lane & 31;
    int b = rp[seg], e = rp[seg + 1];
    float acc[8] = {};
    for (int j = b; j < e; j++) {
        uint4 v = *(const uint4*)&Xbf[(long)esrc[j] * 256 + l5 * 8];
        const short* ps = (const short*)&v;
        #pragma unroll
        for (int q = 0; q < 8; q++) acc[q] += bf2f(ps[q]);
    }
    float inv = (e > b) ? 1.f / (float)(e - b) : 0.f;
    short out[8];
    #pragma unroll
    for (int q = 0; q < 8; q++) out[q] = f2bf(acc[q] * inv);
    *(uint4*)&Abig[((long)(seg >> 4) * 17 + (seg & 15)) * 256 + l5 * 8] = *(const uint4*)out;
}

// ---- root slot copy: Abig[(m*17+16)*256+..] = Xbf[m][..] (16B per thread) ----
__global__ void cvt_root_k(const short* __restrict__ Xbf, short* __restrict__ Abig) {
    int i = blockIdx.x * 256 + threadIdx.x;
    if (i >= NN * 32) return;
    int m = i >> 5, g = i & 31;
    *(uint4*)&Abig[((long)m * 17 + 16) * 256 + g * 8] =
        *(const uint4*)&Xbf[(long)m * 256 + g * 8];
}

// ---- GEMM partial: Cpart[z][m][o] = sum_{k in chunk z} Abig[m][k]*WT[o][k] ----
// BM=64, BN=full N (A read exactly once), BK=64, 4 waves.
// XOR swizzle: LDS slot s of row r holds global 16B-chunk s^(r&7); read of
// logical chunk c fetches slot c^(r&7). Per-16-lane-phase: 8 slots x 2 lanes
// = 2-way bank aliasing = free.
template <int BN, int KCH>
__global__ __launch_bounds__(256, 3) void gemm_k(const short* __restrict__ A,
                                                 const short* __restrict__ WT,
                                                 float* __restrict__ Cpart) {
    constexpr int WC = BN / 64;      // wave-cols (4 or 2)
    constexpr int WR = 4 / WC;       // wave-rows (1 or 2)
    constexpr int FM = 4 / WR;       // m-frags per wave (4 or 2)
    constexpr int BSR = BN / 32;     // Bs staging rounds (8 or 4)

    __shared__ __align__(16) short As[64 * 64];
    __shared__ __align__(16) short Bs[BN * 64];

    const int tid = threadIdx.x;
    const int lane = tid & 63;
    const int w = tid >> 6;
    const int wr = w / WC, wc = w % WC;
    const int m0 = blockIdx.x * 64;
    const int kbase = blockIdx.y * KCH;

    const int al = lane & 15;
    const int cl = lane >> 4;

    // staging source offsets (shorts): chunk ci = i*256+tid -> row=ci>>3, slot=ci&7,
    // global chunk g = slot ^ (row&7)
    int gsrcA[2];
    #pragma unroll
    for (int i = 0; i < 2; i++) {
        int ci = i * 256 + tid;
        int row = ci >> 3;
        int g = (ci & 7) ^ (row & 7);
        gsrcA[i] = row * KTOT + g * 8;
    }
    int gsrcB[BSR];
    #pragma unroll
    for (int i = 0; i < BSR; i++) {
        int ci = i * 256 + tid;
        int row = ci >> 3;
        int g = (ci & 7) ^ (row & 7);
        gsrcB[i] = row * KTOT + g * 8;
    }

    // read offsets (shorts)
    int aoff[FM][2], boff[4][2];
    #pragma unroll
    for (int fm = 0; fm < FM; fm++)
        #pragma unroll
        for (int k2 = 0; k2 < 2; k2++) {
            int row = wr * (64 / WR) + fm * 16 + al;
            int slot = ((k2 << 2) | cl) ^ (row & 7);
            aoff[fm][k2] = (row << 6) + (slot << 3);
        }
    #pragma unroll
    for (int fn = 0; fn < 4; fn++)
        #pragma unroll
        for (int k2 = 0; k2 < 2; k2++) {
            int row = wc * 64 + fn * 16 + al;
            int slot = ((k2 << 2) | cl) ^ (row & 7);
            boff[fn][k2] = (row << 6) + (slot << 3);
        }

    f32x4 acc[FM][4] = {};
    const short* abase = A + (long)m0 * KTOT + kbase;
    const short* bbase = WT + kbase;

    for (int kk = 0; kk < KCH; kk += 64) {
        #pragma unroll
        for (int i = 0; i < 2; i++)
            gl16(abase + kk + gsrcA[i], &As[i * 2048 + w * 512]);
        #pragma unroll
        for (int i = 0; i < BSR; i++)
            gl16(bbase + kk + gsrcB[i], &Bs[i * 2048 + w * 512]);
        __syncthreads();

        bf16x8 a[FM][2], b[4][2];
        #pragma unroll
        for (int fm = 0; fm < FM; fm++)
            #pragma unroll
            for (int k2 = 0; k2 < 2; k2++)
                a[fm][k2] = *(const bf16x8*)&As[aoff[fm][k2]];
        #pragma unroll
        for (int fn = 0; fn < 4; fn++)
            #pragma unroll
            for (int k2 = 0; k2 < 2; k2++)
                b[fn][k2] = *(const bf16x8*)&Bs[boff[fn][k2]];
        #pragma unroll
        for (int k2 = 0; k2 < 2; k2++)
            #pragma unroll
            for (int fm = 0; fm < FM; fm++)
                #pragma unroll
                for (int fn = 0; fn < 4; fn++)
                    acc[fm][fn] = __builtin_amdgcn_mfma_f32_16x16x32_bf16(
                        a[fm][k2], b[fn][k2], acc[fm][fn], 0, 0, 0);
        __syncthreads();
    }

    // epilogue: C/D frag col=lane&15, row=(lane>>4)*4+j
    const int r4 = (lane >> 4) << 2;
    #pragma unroll
    for (int fm = 0; fm < FM; fm++) {
        const int mbase = m0 + wr * (64 / WR) + fm * 16 + r4;
        #pragma unroll
        for (int j = 0; j < 4; j++) {
            const int m = mbase + j;
            if (m < NN) {
                float* cp = Cpart + ((long)blockIdx.y * NN + m) * BN + wc * 64 + al;
                #pragma unroll
                for (int fn = 0; fn < 4; fn++)
                    cp[fn * 16] = acc[fm][fn][j];
            }
        }
    }
}

// ---- reduce K-partials + bias (+ReLU), output bf16 or f32 ----
template <int NOUT, int KS, bool RELU, bool BF16OUT>
__global__ void reduce_k(const float* __restrict__ Cpart, const float* __restrict__ bias,
                         void* __restrict__ out) {
    constexpr int G = NOUT / 4;
    int i = blockIdx.x * 256 + threadIdx.x;  // one per 4 cols
    if (i >= NN * G) return;
    int m = i / G, g = i % G;
    f32x4 sv = {};
    #pragma unroll
    for (int z = 0; z < KS; z++)
        sv += *(const f32x4*)&Cpart[((long)z * NN + m) * NOUT + g * 4];
    sv += *(const f32x4*)&bias[g * 4];
    if (RELU) {
        sv.x = fmaxf(sv.x, 0.f); sv.y = fmaxf(sv.y, 0.f);
        sv.z = fmaxf(sv.z, 0.f); sv.w = fmaxf(sv.w, 0.f);
    }
    if (BF16OUT) {
        s16x4 pk = { f2bf(sv.x), f2bf(sv.y), f2bf(sv.z), f2bf(sv.w) };
        *(s16x4*)((short*)out + (long)i * 4) = pk;
    } else {
        *(f32x4*)((float*)out + (long)i * 4) = sv;
    }
}

extern "C" void kernel_launch(void* const* d_in, const int* in_sizes, int n_in,
                              void* d_out, int out_size, void* d_ws, size_t ws_size,
                              hipStream_t stream) {
    const float* x      = (const float*)d_in[0];
    const int*   ei     = (const int*)d_in[1];
    const int*   et     = (const int*)d_in[2];
    const float* basis1 = (const float*)d_in[3];
    const float* comp1  = (const float*)d_in[4];
    const float* root1  = (const float*)d_in[5];
    const float* bias1  = (const float*)d_in[6];
    const float* basis2 = (const float*)d_in[7];
    const float* comp2  = (const float*)d_in[8];
    const float* root2  = (const float*)d_in[9];
    const float* bias2  = (const float*)d_in[10];
    const int* src = ei;
    const int* dst = ei + EE;

    char* p = (char*)d_ws;
    auto take = [&](size_t bytes) { char* q = p; p += (bytes + 255) & ~(size_t)255; return q; };
    short* Abig  = (short*)take((size_t)MP * 17 * 256 * 2);    // 87.4 MB (padded M)
    short* WT1   = (short*)take((size_t)HIDF * KTOT * 2);
    short* WT2   = (short*)take((size_t)OUTF * KTOT * 2);
    float* Wtmp1 = (float*)take((size_t)KTOT * HIDF * 4);
    float* Wtmp2 = (float*)take((size_t)KTOT * OUTF * 4);
    short* Xbf   = (short*)take((size_t)NN * 256 * 2);
    short* Hbf   = (short*)take((size_t)NN * 256 * 2);
    float* Cpart = (float*)take((size_t)4 * NN * 256 * 4);     // 41 MB, reused both layers
    int*   cnt   = (int*)take((size_t)NSEG * 4);
    int*   incl  = (int*)take((size_t)NSEG * 4);
    int*   rowp  = (int*)take((size_t)(NSEG + 1) * 4);
    int*   fpos  = (int*)take((size_t)NSEG * 4);
    int*   bsum  = (int*)take(1024 * 4);
    int*   esrc  = (int*)take((size_t)EE * 4);

    const int NB1 = (NSEG + 255) / 256;  // 625

    hipMemsetAsync(cnt, 0, (size_t)NSEG * 4, stream);

    // weights
    w1_k<HIDF><<<(int)(((long)KTOT * HIDF + 255) / 256), 256, 0, stream>>>(basis1, comp1, root1, Wtmp1);
    w1_k<OUTF><<<(int)(((long)KTOT * OUTF + 255) / 256), 256, 0, stream>>>(basis2, comp2, root2, Wtmp2);
    {
        dim3 g1(KTOT / 32, HIDF / 32), g2(KTOT / 32, OUTF / 32);
        tr_k<HIDF><<<g1, 256, 0, stream>>>(Wtmp1, WT1);
        tr_k<OUTF><<<g2, 256, 0, stream>>>(Wtmp2, WT2);
    }

    // CSR
    count_k<<<(EE + 255) / 256, 256, 0, stream>>>(dst, et, cnt);
    scan1_k<<<NB1, 256, 0, stream>>>(cnt, incl, bsum);
    scan2_k<<<1, 1024, 0, stream>>>(bsum, NB1);
    scan3_k<<<NB1, 256, 0, stream>>>(cnt, incl, bsum, rowp, fpos);
    fill_k<<<(EE + 255) / 256, 256, 0, stream>>>(src, dst, et, fpos, esrc);

    // X -> bf16
    cvtbf_k<<<(NN * 64 + 255) / 256, 256, 0, stream>>>(x, Xbf);

    // layer 1
    agg_k<<<(NSEG / 2 * 64 + 255) / 256, 256, 0, stream>>>(rowp, esrc, Xbf, Abig);
    cvt_root_k<<<(NN * 32 + 255) / 256, 256, 0, stream>>>(Xbf, Abig);
    {
        dim3 g(MP / 64, 4);  // KS=4, KCH=1088
        gemm_k<HIDF, 1088><<<g, 256, 0, stream>>>(Abig, WT1, Cpart);
    }
    reduce_k<HIDF, 4, true, true><<<(NN * 64 + 255) / 256, 256, 0, stream>>>(Cpart, bias1, Hbf);

    // layer 2
    agg_k<<<(NSEG / 2 * 64 + 255) / 256, 256, 0, stream>>>(rowp, esrc, Hbf, Abig);
    cvt_root_k<<<(NN * 32 + 255) / 256, 256, 0, stream>>>(Hbf, Abig);
    {
        dim3 g(MP / 64, 4);  // KS=4, KCH=1088
        gemm_k<OUTF, 1088><<<g, 256, 0, stream>>>(Abig, WT2, Cpart);
    }
    reduce_k<OUTF, 4, false, false><<<(NN * 32 + 255) / 256, 256, 0, stream>>>(Cpart, bias2, (float*)d_out);
}